// Round 10
// baseline (477.859 us; speedup 1.0000x reference)
//
#include <hip/hip_runtime.h>
#include <stdint.h>

typedef unsigned short u16;
typedef __attribute__((ext_vector_type(8))) short bf16x8;
typedef __attribute__((ext_vector_type(4))) float f32x4;

#define TOKENS 8192
#define DM 1024
#define NE 8
#define DH 4096
#define CAP 2048

__device__ __forceinline__ u16 f2bf(float f) {
  unsigned int u = __float_as_uint(f);
  u = u + 0x7FFFu + ((u >> 16) & 1u);
  return (u16)(u >> 16);
}
__device__ __forceinline__ float bf2f(u16 u) {
  return __uint_as_float(((unsigned int)u) << 16);
}

__device__ __forceinline__ void gll16(const void* g, void* l) {
  __builtin_amdgcn_global_load_lds(
      (const __attribute__((address_space(1))) unsigned int*)g,
      (__attribute__((address_space(3))) unsigned int*)l, 16, 0, 0);
}

// ---------------- gating: logits (double accum) + softmax + top2 ----------------
__global__ __launch_bounds__(256) void gating_kernel(
    const float* __restrict__ x, const float* __restrict__ wg,
    int* __restrict__ idx1, int* __restrict__ idx2,
    float* __restrict__ g1r, float* __restrict__ g2r, float* __restrict__ me) {
  __shared__ float gsh[4][8];
  int lane = threadIdx.x & 63;
  int w = threadIdx.x >> 6;
  int t = blockIdx.x * 4 + w;
  const float* xr = x + (size_t)t * DM;
  double acc[8];
#pragma unroll
  for (int e = 0; e < 8; ++e) acc[e] = 0.0;
#pragma unroll
  for (int it = 0; it < 4; ++it) {
    float4 xv = ((const float4*)xr)[it * 64 + lane];
    int base = (it * 64 + lane) * 4;
    const float* wr = wg + (size_t)base * 8;
    float xs[4] = {xv.x, xv.y, xv.z, xv.w};
#pragma unroll
    for (int j = 0; j < 4; ++j)
#pragma unroll
      for (int e = 0; e < 8; ++e) acc[e] += (double)xs[j] * (double)wr[j * 8 + e];
  }
#pragma unroll
  for (int off = 32; off > 0; off >>= 1)
#pragma unroll
    for (int e = 0; e < 8; ++e) acc[e] += __shfl_down(acc[e], off);
  if (lane == 0) {
    float l[8];
#pragma unroll
    for (int e = 0; e < 8; ++e) l[e] = (float)acc[e];
    int i1 = 0;
    float v1 = l[0];
#pragma unroll
    for (int e = 1; e < 8; ++e)
      if (l[e] > v1) { v1 = l[e]; i1 = e; }
    int i2 = -1;
    float v2 = -3.4e38f;
#pragma unroll
    for (int e = 0; e < 8; ++e)
      if (e != i1 && l[e] > v2) { v2 = l[e]; i2 = e; }
    float s = 0.f;
    float p[8];
#pragma unroll
    for (int e = 0; e < 8; ++e) { p[e] = expf(l[e] - v1); s += p[e]; }
    float inv = 1.f / s;
    idx1[t] = i1;
    idx2[t] = i2;
    g1r[t] = inv;                    // p[i1] == 1
    g2r[t] = expf(v2 - v1) * inv;
#pragma unroll
    for (int e = 0; e < 8; ++e) gsh[w][e] = p[e] * inv;
  }
  __syncthreads();
  if (threadIdx.x < 8) {
    int e = threadIdx.x;
    atomicAdd(&me[e], gsh[0][e] + gsh[1][e] + gsh[2][e] + gsh[3][e]);
  }
}

// -------- single-block scan: per-expert exclusive prefix, capacity, slots, laux --------
__global__ __launch_bounds__(1024) void scan_kernel(
    const int* __restrict__ idx1, const int* __restrict__ idx2,
    const float* __restrict__ g1r, const float* __restrict__ g2r,
    const float* __restrict__ me,
    int* __restrict__ slot1, int* __restrict__ slot2,
    float* __restrict__ g1n, float* __restrict__ g2n,
    int* __restrict__ slot2tok, float* __restrict__ laux) {
  __shared__ u16 c[16][1024];
  __shared__ u16 csum[16][32];
  __shared__ int tot[16];
  int tid = threadIdx.x;
  int i1[8], i2[8];
#pragma unroll
  for (int ctr = 0; ctr < 16; ++ctr) c[ctr][tid] = 0;
#pragma unroll
  for (int j = 0; j < 8; ++j) {
    int t = tid * 8 + j;
    i1[j] = idx1[t];
    i2[j] = idx2[t];
    c[i1[j]][tid]++;
    c[8 + i2[j]][tid]++;
  }
  __syncthreads();
  if (tid < 512) {
    int ctr = tid >> 5, ch = tid & 31;
    int s = 0;
#pragma unroll
    for (int i = 0; i < 32; ++i) s += c[ctr][ch * 32 + i];
    csum[ctr][ch] = (u16)s;
  }
  __syncthreads();
  if (tid < 16) {
    int run = 0;
#pragma unroll
    for (int ch = 0; ch < 32; ++ch) {
      int v = csum[tid][ch];
      csum[tid][ch] = (u16)run;
      run += v;
    }
    tot[tid] = run;
  }
  __syncthreads();
  if (tid < 512) {
    int ctr = tid >> 5, ch = tid & 31;
    int run = csum[ctr][ch];
#pragma unroll
    for (int i = 0; i < 32; ++i) {
      int v = c[ctr][ch * 32 + i];
      c[ctr][ch * 32 + i] = (u16)run;
      run += v;
    }
  }
  __syncthreads();
#pragma unroll
  for (int j = 0; j < 8; ++j) {
    int t = tid * 8 + j;
    int e1 = i1[j], e2 = i2[j];
    int L1 = c[e1][tid]++;
    int L2 = c[8 + e2][tid]++;
    L2 += tot[e2];
    bool kv1 = L1 < CAP, kv2 = L2 < CAP;
    float G1 = kv1 ? g1r[t] : 0.f;
    float G2 = kv2 ? g2r[t] : 0.f;
    float den = fmaxf(G1 + G2, 1e-9f);
    g1n[t] = G1 / den;
    g2n[t] = G2 / den;
    int s1 = kv1 ? (e1 * CAP + L1) : -1;
    int s2 = kv2 ? (e2 * CAP + L2) : -1;
    slot1[t] = s1;
    slot2[t] = s2;
    if (kv1) slot2tok[s1] = t;
    if (kv2) slot2tok[s2] = t;
  }
  if (tid == 0) {
    double a = 0.0;
    for (int e = 0; e < 8; ++e)
      a += ((double)me[e] / 8192.0) * ((double)tot[e] / 8192.0);
    laux[0] = (float)(a * 8.0);  // mean(me*ce)*E*E = (sum/8)*64
  }
}

// ------- transpose fp32 [E][R][C] -> bf16 [E][C][R], 64x64 tile, vectorized -------
__global__ __launch_bounds__(256) void transpose_kernel(const float* __restrict__ src,
                                                        u16* __restrict__ dst, int R, int C) {
  __shared__ float tile[64][65];
  const int tid = threadIdx.x;
  const int r0 = blockIdx.y * 64, c0 = blockIdx.x * 64;
  const float* s = src + (size_t)blockIdx.z * R * C;
  u16* d = dst + (size_t)blockIdx.z * R * C;
  const int lr = tid >> 4;          // 0..15
  const int lc = (tid & 15) * 4;    // 0..60
#pragma unroll
  for (int i = 0; i < 4; ++i) {
    const float4 v = *(const float4*)&s[(size_t)(r0 + i * 16 + lr) * C + c0 + lc];
    tile[i * 16 + lr][lc] = v.x;
    tile[i * 16 + lr][lc + 1] = v.y;
    tile[i * 16 + lr][lc + 2] = v.z;
    tile[i * 16 + lr][lc + 3] = v.w;
  }
  __syncthreads();
  const int oc = tid >> 3;        // 0..31 (output row = input col)
  const int orr = (tid & 7) * 8;  // 0..56 (output col base = input row)
#pragma unroll
  for (int i = 0; i < 2; ++i) {
    const int c = oc + i * 32;
    u16 o[8];
#pragma unroll
    for (int j = 0; j < 8; ++j) o[j] = f2bf(tile[orr + j][c]);
    *(uint4*)&d[(size_t)(c0 + c) * R + r0 + orr] = *(const uint4*)o;
  }
}

// ---------------- gather tokens to expert buffers (bf16) ----------------
__global__ void gather_kernel(const float* __restrict__ x, const int* __restrict__ slot2tok,
                              u16* __restrict__ xe) {
  int slot = blockIdx.y * CAP + blockIdx.x;
  int tok = slot2tok[slot];
  int tid = threadIdx.x;  // 128
  u16 o[8];
  if (tok >= 0) {
    const float4* xr = (const float4*)(x + (size_t)tok * DM);
    float4 a = xr[tid * 2], b = xr[tid * 2 + 1];
    o[0] = f2bf(a.x); o[1] = f2bf(a.y); o[2] = f2bf(a.z); o[3] = f2bf(a.w);
    o[4] = f2bf(b.x); o[5] = f2bf(b.y); o[6] = f2bf(b.z); o[7] = f2bf(b.w);
  } else {
#pragma unroll
    for (int j = 0; j < 8; ++j) o[j] = 0;
  }
  *(uint4*)(xe + (size_t)slot * DM + tid * 8) = *(const uint4*)o;
}

// ------- 256x256 8-phase bf16 GEMM + B-side read-ahead (T1+T2+T3+T4+T5) -------
// vs R5: b23 reads hoisted to P1 (b23 regs dead since prev Q4); b01-next reads
// hoisted into P4/P8's MFMA region AFTER vmcnt(6)+BAR (next buffer visible
// there by construction). Counted lgkm: P1 lgkm(4) [leave b23 in flight],
// P2/P3 lgkm(0), P4 lgkm(4) [leave b01' in flight under Q4's MFMA].
// Staging placement and vmcnt positions identical to the verified R5 schedule.
#define BAR()                              \
  {                                        \
    asm volatile("" ::: "memory");         \
    __builtin_amdgcn_s_barrier();          \
    asm volatile("" ::: "memory");         \
  }
#define VMCNT(n) asm volatile("s_waitcnt vmcnt(" #n ")" ::: "memory")
#define LGKM(n) asm volatile("s_waitcnt lgkmcnt(" #n ")" ::: "memory")

template <int RELU, int OUTBF16>
__global__ __launch_bounds__(512, 2) void gemm_kernel(
    const u16* __restrict__ A, const u16* __restrict__ Bt,
    const float* __restrict__ bias, void* __restrict__ Cv,
    int MO, int NO, int K) {
  __shared__ __align__(16) u16 As[2][256 * 64];
  __shared__ __align__(16) u16 Bs[2][256 * 64];
  const int tid = threadIdx.x;
  const int lane = tid & 63, wid = tid >> 6;
  const int wm = wid >> 2, wn = wid & 3;

  // T1: XCD-bijective swizzle — XCD k owns a contiguous x-major chunk (= expert k).
  const int gx = gridDim.x, gy = gridDim.y;
  const int nwg = gx * gy * gridDim.z;      // multiple of 8
  const int L = (blockIdx.z * gy + blockIdx.y) * gx + blockIdx.x;
  const int cpx = nwg >> 3;
  const int Ls = (L & 7) * cpx + (L >> 3);
  const int bx = Ls % gx;
  const int tq = Ls / gx;
  const int by = tq % gy;
  const int eb = tq / gy;

  const size_t Ks2 = (size_t)K * 2;
  const char* Ag = (const char*)(A + (size_t)eb * MO * K + (size_t)by * 256 * K);
  const char* Bg = (const char*)(Bt + (size_t)eb * NO * K + (size_t)bx * 256 * K);
  const int rl = tid >> 3;
  const int sb = ((tid & 7) * 16) ^ ((rl & 7) << 4);  // pre-swizzled src byte col (T2)
  Ag += (size_t)rl * Ks2 + sb;
  Bg += (size_t)rl * Ks2 + sb;
  char* AsB = ((char*)As) + tid * 16;
  char* BsB = ((char*)Bs) + tid * 16;
  const u16* AsE = &As[0][0];
  const u16* BsE = &Bs[0][0];
  const int fr = lane & 15, kg8 = (lane >> 4) * 8;
  const int swz = (fr & 7) << 3;  // read-side element XOR (T2)

#define STAGE_A(BUF_, REG_, KT_) \
  gll16(Ag + (size_t)((REG_)*64) * Ks2 + (size_t)(KT_)*128, AsB + (BUF_)*32768 + (REG_)*8192)
#define STAGE_B(BUF_, REG_, KT_) \
  gll16(Bg + (size_t)((REG_)*64) * Ks2 + (size_t)(KT_)*128, BsB + (BUF_)*32768 + (REG_)*8192)
#define LDA(BUF_, M_, K_) \
  (*(const bf16x8*)&AsE[(BUF_)*16384 + (wm * 128 + (M_)*16 + fr) * 64 + (((K_)*32 + kg8) ^ swz)])
#define LDB(BUF_, N_, K_) \
  (*(const bf16x8*)&BsE[(BUF_)*16384 + (wn * 64 + (N_)*16 + fr) * 64 + (((K_)*32 + kg8) ^ swz)])
// k OUTER: 8 independent MFMAs per k-step (dependent pairs 8 apart)
#define MFMA_Q(MB_, NB_)                                                            \
  _Pragma("unroll") for (int k = 0; k < 2; ++k)                                     \
  _Pragma("unroll") for (int m = 0; m < 4; ++m)                                     \
  _Pragma("unroll") for (int n = 0; n < 2; ++n)                                     \
      acc[(MB_) + m][(NB_) + n] = __builtin_amdgcn_mfma_f32_16x16x32_bf16(          \
          areg[m][k], breg[(NB_) + n][k], acc[(MB_) + m][(NB_) + n], 0, 0, 0)

#define RD_A03(C_)                                                \
  _Pragma("unroll") for (int m = 0; m < 4; ++m) {                 \
    areg[m][0] = LDA(C_, m, 0); areg[m][1] = LDA(C_, m, 1);       \
  }
#define RD_A47(C_)                                                \
  _Pragma("unroll") for (int m = 0; m < 4; ++m) {                 \
    areg[m][0] = LDA(C_, 4 + m, 0); areg[m][1] = LDA(C_, 4 + m, 1); \
  }
#define RD_B01(C_)                                                \
  _Pragma("unroll") for (int n = 0; n < 2; ++n) {                 \
    breg[n][0] = LDB(C_, n, 0); breg[n][1] = LDB(C_, n, 1);       \
  }
#define RD_B23(C_)                                                \
  _Pragma("unroll") for (int n = 2; n < 4; ++n) {                 \
    breg[n][0] = LDB(C_, n, 0); breg[n][1] = LDB(C_, n, 1);       \
  }
#define MMW(N_, MB_, NB_)                     \
  LGKM(N_);                                   \
  __builtin_amdgcn_sched_barrier(0);          \
  __builtin_amdgcn_s_setprio(1);              \
  MFMA_Q(MB_, NB_);                           \
  __builtin_amdgcn_s_setprio(0);              \
  BAR();

  f32x4 acc[8][4];
#pragma unroll
  for (int i = 0; i < 8; ++i)
#pragma unroll
    for (int j = 0; j < 4; ++j) acc[i][j] = {0.f, 0.f, 0.f, 0.f};
  bf16x8 areg[4][2], breg[4][2];

  const int NT = K >> 6;  // >= 2, even

  // prologue: tile0 full (8) + tile1 pairs #1-3 (6); vmcnt(6) retires tile0.
  STAGE_A(0, 0, 0); STAGE_A(0, 1, 0); STAGE_A(0, 2, 0); STAGE_A(0, 3, 0);
  STAGE_B(0, 0, 0); STAGE_B(0, 1, 0); STAGE_B(0, 2, 0); STAGE_B(0, 3, 0);
  STAGE_A(1, 0, 1); STAGE_A(1, 2, 1);
  STAGE_B(1, 0, 1); STAGE_B(1, 1, 1);
  STAGE_B(1, 2, 1); STAGE_B(1, 3, 1);
  VMCNT(6);
  BAR();
  RD_B01(0);  // prefetch b01 for tile 0 (steady-state invariant)

  for (int t = 0; t < NT; t += 2) {
    const int t2 = (t + 2 < NT) ? t + 2 : NT - 2;  // tail: identical-data re-stage
    const int t3 = (t + 3 < NT) ? t + 3 : NT - 1;
    // ---- K-tile t (buf0) ----
    // P1: reads a03 + b23(hoisted) | stage (t+1)->buf1 Ra1,Ra3
    RD_A03(0); RD_B23(0);
    STAGE_A(1, 1, t + 1); STAGE_A(1, 3, t + 1);
    BAR();
    MMW(4, 0, 0);   // wait a03+b01(prefetched); b23 stays in flight
    // P2: no reads | stage (t+2)->buf0 Ra0,Ra2 (a03 read done P1)
    STAGE_A(0, 0, t2); STAGE_A(0, 2, t2);
    BAR();
    MMW(0, 0, 2);   // wait b23
    // P3: reads a47 | stage (t+2)->buf0 Rb0,Rb1 (b01 read done prev P8)
    RD_A47(0);
    STAGE_B(0, 0, t2); STAGE_B(0, 1, t2);
    BAR();
    MMW(0, 4, 0);   // wait a47
    // P4: stage (t+2)->buf0 Rb2,Rb3 | vmcnt(6): buf1(t+1) complete | prefetch b01(buf1)
    STAGE_B(0, 2, t2); STAGE_B(0, 3, t2);
    VMCNT(6);
    BAR();
    RD_B01(1);
    MMW(4, 4, 2);   // Q4 operands resident; b01' flows under MFMA
    // ---- K-tile t+1 (buf1) ----
    RD_A03(1); RD_B23(1);
    STAGE_A(0, 1, t2); STAGE_A(0, 3, t2);
    BAR();
    MMW(4, 0, 0);
    STAGE_A(1, 0, t3); STAGE_A(1, 2, t3);
    BAR();
    MMW(0, 0, 2);
    RD_A47(1);
    STAGE_B(1, 0, t3); STAGE_B(1, 1, t3);
    BAR();
    MMW(0, 4, 0);
    STAGE_B(1, 2, t3); STAGE_B(1, 3, t3);
    VMCNT(6);
    BAR();
    RD_B01(0);
    MMW(4, 4, 2);
  }

  // epilogue: C row = row0 + m*16 + r, col = col0 + n*16
  const int row0 = by * 256 + wm * 128 + (kg8 >> 3) * 4;
  const int col0 = bx * 256 + wn * 64 + fr;
  const float* be = bias + (size_t)eb * NO;
  size_t cbase = (size_t)eb * MO * NO;
#pragma unroll
  for (int m = 0; m < 8; ++m) {
#pragma unroll
    for (int n = 0; n < 4; ++n) {
      int col = col0 + n * 16;
      float bv = be[col];
#pragma unroll
      for (int r = 0; r < 4; ++r) {
        int row = row0 + m * 16 + r;
        float v = acc[m][n][r] + bv;
        if (RELU) v = fmaxf(v, 0.f);
        if (OUTBF16)
          ((u16*)Cv)[cbase + (size_t)row * NO + col] = f2bf(v);
        else
          ((float*)Cv)[cbase + (size_t)row * NO + col] = v;
      }
    }
  }
#undef MMW
#undef RD_A03
#undef RD_A47
#undef RD_B01
#undef RD_B23
#undef STAGE_A
#undef STAGE_B
#undef LDA
#undef LDB
#undef MFMA_Q
}

// ------------- combine: out[t] = g1*eo[slot1] + g2*eo[slot2] (bf16 eo) -------------
__global__ void combine_kernel(const u16* __restrict__ eo,
                               const float* __restrict__ g1n, const float* __restrict__ g2n,
                               const int* __restrict__ slot1, const int* __restrict__ slot2,
                               float* __restrict__ out) {
  int t = blockIdx.x, tid = threadIdx.x;  // 256 threads x 4 fp32
  float g1 = g1n[t], g2 = g2n[t];
  int s1 = slot1[t], s2 = slot2[t];
  float o0 = 0.f, o1 = 0.f, o2 = 0.f, o3 = 0.f;
  if (s1 >= 0) {
    ushort4 a = ((const ushort4*)(eo + (size_t)s1 * DM))[tid];
    o0 = g1 * bf2f(a.x); o1 = g1 * bf2f(a.y); o2 = g1 * bf2f(a.z); o3 = g1 * bf2f(a.w);
  }
  if (s2 >= 0) {
    ushort4 b = ((const ushort4*)(eo + (size_t)s2 * DM))[tid];
    o0 += g2 * bf2f(b.x); o1 += g2 * bf2f(b.y); o2 += g2 * bf2f(b.z); o3 += g2 * bf2f(b.w);
  }
  ((float4*)(out + (size_t)t * DM))[tid] = make_float4(o0, o1, o2, o3);
}

extern "C" void kernel_launch(void* const* d_in, const int* in_sizes, int n_in,
                              void* d_out, int out_size, void* d_ws, size_t ws_size,
                              hipStream_t stream) {
  const float* x = (const float*)d_in[0];
  const float* wg = (const float*)d_in[1];
  const float* w1 = (const float*)d_in[2];
  const float* b1 = (const float*)d_in[3];
  const float* w2 = (const float*)d_in[4];
  const float* b2 = (const float*)d_in[5];
  float* out = (float*)d_out;

  const size_t SZ_WT1 = (size_t)NE * DH * DM * 2;   // 64 MB bf16 (aliased: eo bf16 32 MB)
  const size_t SZ_WT2 = (size_t)NE * DM * DH * 2;   // 64 MB
  const size_t SZ_XE = (size_t)NE * CAP * DM * 2;   // 32 MB
  const size_t SZ_H = (size_t)NE * CAP * DH * 2;    // 128 MB
  const size_t SZ_TOK = (size_t)TOKENS * 4;

  char* p = (char*)d_ws;
  u16* wt1 = (u16*)p;               // aliased region: wt1 (gemm1) then eo bf16 (gemm2)
  u16* eo = (u16*)p;                p += SZ_WT1;
  u16* wt2 = (u16*)p;               p += SZ_WT2;
  u16* xe = (u16*)p;                p += SZ_XE;
  u16* h = (u16*)p;                 p += SZ_H;
  int* idx1 = (int*)p;              p += SZ_TOK;
  int* idx2 = (int*)p;              p += SZ_TOK;
  int* slot1 = (int*)p;             p += SZ_TOK;
  int* slot2 = (int*)p;             p += SZ_TOK;
  float* g1r = (float*)p;           p += SZ_TOK;
  float* g2r = (float*)p;           p += SZ_TOK;
  float* g1n = (float*)p;           p += SZ_TOK;
  float* g2n = (float*)p;           p += SZ_TOK;
  int* slot2tok = (int*)p;          p += (size_t)NE * CAP * 4;
  float* me = (float*)p;            p += 256;
  if ((size_t)(p - (char*)d_ws) > ws_size) return;  // ws too small: fail loudly via absmax

  hipMemsetAsync(me, 0, 32, stream);
  hipMemsetAsync(slot2tok, 0xFF, (size_t)NE * CAP * 4, stream);

  gating_kernel<<<TOKENS / 4, 256, 0, stream>>>(x, wg, idx1, idx2, g1r, g2r, me);
  scan_kernel<<<1, 1024, 0, stream>>>(idx1, idx2, g1r, g2r, me, slot1, slot2, g1n, g2n,
                                      slot2tok, out + (size_t)TOKENS * DM);
  // w1 [E][1024][4096] -> wt1 [E][4096][1024]
  transpose_kernel<<<dim3(DH / 64, DM / 64, NE), 256, 0, stream>>>(w1, wt1, DM, DH);
  // w2 [E][4096][1024] -> wt2 [E][1024][4096]
  transpose_kernel<<<dim3(DM / 64, DH / 64, NE), 256, 0, stream>>>(w2, wt2, DH, DM);
  gather_kernel<<<dim3(CAP, NE), 128, 0, stream>>>(x, slot2tok, xe);
  // h = relu(xe @ w1 + b1)  : [E][2048][4096] bf16
  gemm_kernel<1, 1><<<dim3(DH / 256, CAP / 256, NE), 512, 0, stream>>>(xe, wt1, b1, (void*)h,
                                                                       CAP, DH, DM);
  // eo = h @ w2 + b2        : [E][2048][1024] bf16 (aliases wt1 region; gemm1 done)
  gemm_kernel<0, 1><<<dim3(DM / 256, CAP / 256, NE), 512, 0, stream>>>(h, wt2, b2, (void*)eo,
                                                                       CAP, DM, DH);
  combine_kernel<<<TOKENS, 256, 0, stream>>>(eo, g1n, g2n, slot1, slot2, out);
}

// Round 11
// 467.001 us; speedup vs baseline: 1.0232x; 1.0232x over previous
//
#include <hip/hip_runtime.h>
#include <stdint.h>

typedef unsigned short u16;
typedef __attribute__((ext_vector_type(8))) short bf16x8;
typedef __attribute__((ext_vector_type(4))) float f32x4;

#define TOKENS 8192
#define DM 1024
#define NE 8
#define DH 4096
#define CAP 2048

__device__ __forceinline__ u16 f2bf(float f) {
  unsigned int u = __float_as_uint(f);
  u = u + 0x7FFFu + ((u >> 16) & 1u);
  return (u16)(u >> 16);
}
__device__ __forceinline__ float bf2f(u16 u) {
  return __uint_as_float(((unsigned int)u) << 16);
}

__device__ __forceinline__ void gll16(const void* g, void* l) {
  __builtin_amdgcn_global_load_lds(
      (const __attribute__((address_space(1))) unsigned int*)g,
      (__attribute__((address_space(3))) unsigned int*)l, 16, 0, 0);
}

// ---------------- gating: logits (double accum) + softmax + top2 ----------------
__global__ __launch_bounds__(256) void gating_kernel(
    const float* __restrict__ x, const float* __restrict__ wg,
    int* __restrict__ idx1, int* __restrict__ idx2,
    float* __restrict__ g1r, float* __restrict__ g2r, float* __restrict__ me) {
  __shared__ float gsh[4][8];
  int lane = threadIdx.x & 63;
  int w = threadIdx.x >> 6;
  int t = blockIdx.x * 4 + w;
  const float* xr = x + (size_t)t * DM;
  double acc[8];
#pragma unroll
  for (int e = 0; e < 8; ++e) acc[e] = 0.0;
#pragma unroll
  for (int it = 0; it < 4; ++it) {
    float4 xv = ((const float4*)xr)[it * 64 + lane];
    int base = (it * 64 + lane) * 4;
    const float* wr = wg + (size_t)base * 8;
    float xs[4] = {xv.x, xv.y, xv.z, xv.w};
#pragma unroll
    for (int j = 0; j < 4; ++j)
#pragma unroll
      for (int e = 0; e < 8; ++e) acc[e] += (double)xs[j] * (double)wr[j * 8 + e];
  }
#pragma unroll
  for (int off = 32; off > 0; off >>= 1)
#pragma unroll
    for (int e = 0; e < 8; ++e) acc[e] += __shfl_down(acc[e], off);
  if (lane == 0) {
    float l[8];
#pragma unroll
    for (int e = 0; e < 8; ++e) l[e] = (float)acc[e];
    int i1 = 0;
    float v1 = l[0];
#pragma unroll
    for (int e = 1; e < 8; ++e)
      if (l[e] > v1) { v1 = l[e]; i1 = e; }
    int i2 = -1;
    float v2 = -3.4e38f;
#pragma unroll
    for (int e = 0; e < 8; ++e)
      if (e != i1 && l[e] > v2) { v2 = l[e]; i2 = e; }
    float s = 0.f;
    float p[8];
#pragma unroll
    for (int e = 0; e < 8; ++e) { p[e] = expf(l[e] - v1); s += p[e]; }
    float inv = 1.f / s;
    idx1[t] = i1;
    idx2[t] = i2;
    g1r[t] = inv;                    // p[i1] == 1
    g2r[t] = expf(v2 - v1) * inv;
#pragma unroll
    for (int e = 0; e < 8; ++e) gsh[w][e] = p[e] * inv;
  }
  __syncthreads();
  if (threadIdx.x < 8) {
    int e = threadIdx.x;
    atomicAdd(&me[e], gsh[0][e] + gsh[1][e] + gsh[2][e] + gsh[3][e]);
  }
}

// -------- single-block scan: per-expert exclusive prefix, capacity, slots, laux --------
__global__ __launch_bounds__(1024) void scan_kernel(
    const int* __restrict__ idx1, const int* __restrict__ idx2,
    const float* __restrict__ g1r, const float* __restrict__ g2r,
    const float* __restrict__ me,
    int* __restrict__ slot1, int* __restrict__ slot2,
    float* __restrict__ g1n, float* __restrict__ g2n,
    int* __restrict__ slot2tok, float* __restrict__ laux) {
  __shared__ u16 c[16][1024];
  __shared__ u16 csum[16][32];
  __shared__ int tot[16];
  int tid = threadIdx.x;
  int i1[8], i2[8];
#pragma unroll
  for (int ctr = 0; ctr < 16; ++ctr) c[ctr][tid] = 0;
#pragma unroll
  for (int j = 0; j < 8; ++j) {
    int t = tid * 8 + j;
    i1[j] = idx1[t];
    i2[j] = idx2[t];
    c[i1[j]][tid]++;
    c[8 + i2[j]][tid]++;
  }
  __syncthreads();
  if (tid < 512) {
    int ctr = tid >> 5, ch = tid & 31;
    int s = 0;
#pragma unroll
    for (int i = 0; i < 32; ++i) s += c[ctr][ch * 32 + i];
    csum[ctr][ch] = (u16)s;
  }
  __syncthreads();
  if (tid < 16) {
    int run = 0;
#pragma unroll
    for (int ch = 0; ch < 32; ++ch) {
      int v = csum[tid][ch];
      csum[tid][ch] = (u16)run;
      run += v;
    }
    tot[tid] = run;
  }
  __syncthreads();
  if (tid < 512) {
    int ctr = tid >> 5, ch = tid & 31;
    int run = csum[ctr][ch];
#pragma unroll
    for (int i = 0; i < 32; ++i) {
      int v = c[ctr][ch * 32 + i];
      c[ctr][ch * 32 + i] = (u16)run;
      run += v;
    }
  }
  __syncthreads();
#pragma unroll
  for (int j = 0; j < 8; ++j) {
    int t = tid * 8 + j;
    int e1 = i1[j], e2 = i2[j];
    int L1 = c[e1][tid]++;
    int L2 = c[8 + e2][tid]++;
    L2 += tot[e2];
    bool kv1 = L1 < CAP, kv2 = L2 < CAP;
    float G1 = kv1 ? g1r[t] : 0.f;
    float G2 = kv2 ? g2r[t] : 0.f;
    float den = fmaxf(G1 + G2, 1e-9f);
    g1n[t] = G1 / den;
    g2n[t] = G2 / den;
    int s1 = kv1 ? (e1 * CAP + L1) : -1;
    int s2 = kv2 ? (e2 * CAP + L2) : -1;
    slot1[t] = s1;
    slot2[t] = s2;
    if (kv1) slot2tok[s1] = t;
    if (kv2) slot2tok[s2] = t;
  }
  if (tid == 0) {
    double a = 0.0;
    for (int e = 0; e < 8; ++e)
      a += ((double)me[e] / 8192.0) * ((double)tot[e] / 8192.0);
    laux[0] = (float)(a * 8.0);  // mean(me*ce)*E*E = (sum/8)*64
  }
}

// --- merged transpose: z<8 -> w1 expert z; z>=8 -> w2 expert z-8 (fp32->bf16, [R][C]->[C][R])
__global__ __launch_bounds__(256) void transpose2_kernel(
    const float* __restrict__ w1, const float* __restrict__ w2,
    u16* __restrict__ wt1, u16* __restrict__ wt2) {
  __shared__ float tile[64][65];
  const int tid = threadIdx.x;
  const int z = blockIdx.z;
  const float* s;
  u16* d;
  int C, r0, c0;
  if (z < 8) {
    s = w1 + (size_t)z * DM * DH;
    d = wt1 + (size_t)z * DM * DH;
    C = DH;  // R = DM
    r0 = blockIdx.y * 64;
    c0 = blockIdx.x * 64;
  } else {
    s = w2 + (size_t)(z - 8) * DM * DH;
    d = wt2 + (size_t)(z - 8) * DM * DH;
    C = DM;  // R = DH
    r0 = blockIdx.x * 64;
    c0 = blockIdx.y * 64;
  }
  const int R = (z < 8) ? DM : DH;
  const int lr = tid >> 4;          // 0..15
  const int lc = (tid & 15) * 4;    // 0..60
#pragma unroll
  for (int i = 0; i < 4; ++i) {
    const float4 v = *(const float4*)&s[(size_t)(r0 + i * 16 + lr) * C + c0 + lc];
    tile[i * 16 + lr][lc] = v.x;
    tile[i * 16 + lr][lc + 1] = v.y;
    tile[i * 16 + lr][lc + 2] = v.z;
    tile[i * 16 + lr][lc + 3] = v.w;
  }
  __syncthreads();
  const int oc = tid >> 3;        // 0..31 (output row = input col)
  const int orr = (tid & 7) * 8;  // 0..56 (output col base = input row)
#pragma unroll
  for (int i = 0; i < 2; ++i) {
    const int c = oc + i * 32;
    u16 o[8];
#pragma unroll
    for (int j = 0; j < 8; ++j) o[j] = f2bf(tile[orr + j][c]);
    *(uint4*)&d[(size_t)(c0 + c) * R + r0 + orr] = *(const uint4*)o;
  }
}

// ---------------- gather tokens to expert buffers (bf16) ----------------
__global__ void gather_kernel(const float* __restrict__ x, const int* __restrict__ slot2tok,
                              u16* __restrict__ xe) {
  int slot = blockIdx.y * CAP + blockIdx.x;
  int tok = slot2tok[slot];
  int tid = threadIdx.x;  // 128
  u16 o[8];
  if (tok >= 0) {
    const float4* xr = (const float4*)(x + (size_t)tok * DM);
    float4 a = xr[tid * 2], b = xr[tid * 2 + 1];
    o[0] = f2bf(a.x); o[1] = f2bf(a.y); o[2] = f2bf(a.z); o[3] = f2bf(a.w);
    o[4] = f2bf(b.x); o[5] = f2bf(b.y); o[6] = f2bf(b.z); o[7] = f2bf(b.w);
  } else {
#pragma unroll
    for (int j = 0; j < 8; ++j) o[j] = 0;
  }
  *(uint4*)(xe + (size_t)slot * DM + tid * 8) = *(const uint4*)o;
}

// ---------------- 256x256 m201 8-phase bf16 GEMM, 16x16x32 (R5-verified) ----------
// Structural plateau note: five schedule variants (2-phase, shallow/deep
// pipeline, coarse 1-barrier, m201 8-phase, B-read-ahead) all measure
// 166-180 us at 0 bank conflicts — sum-of-pipes bound (MFMA 2480 +
// LDS-read ~2260 cyc/K-tile, no overlap at 1 block/CU). Do not re-tune.
#define BAR()                              \
  {                                        \
    asm volatile("" ::: "memory");         \
    __builtin_amdgcn_s_barrier();          \
    asm volatile("" ::: "memory");         \
  }
#define VMCNT(n) asm volatile("s_waitcnt vmcnt(" #n ")" ::: "memory")
#define LGKM(n) asm volatile("s_waitcnt lgkmcnt(" #n ")" ::: "memory")

template <int RELU, int OUTBF16>
__global__ __launch_bounds__(512, 2) void gemm_kernel(
    const u16* __restrict__ A, const u16* __restrict__ Bt,
    const float* __restrict__ bias, void* __restrict__ Cv,
    int MO, int NO, int K) {
  __shared__ __align__(16) u16 As[2][256 * 64];
  __shared__ __align__(16) u16 Bs[2][256 * 64];
  const int tid = threadIdx.x;
  const int lane = tid & 63, wid = tid >> 6;
  const int wm = wid >> 2, wn = wid & 3;

  // T1: XCD-bijective swizzle — XCD k owns a contiguous x-major chunk (= expert k).
  const int gx = gridDim.x, gy = gridDim.y;
  const int nwg = gx * gy * gridDim.z;      // multiple of 8
  const int L = (blockIdx.z * gy + blockIdx.y) * gx + blockIdx.x;
  const int cpx = nwg >> 3;
  const int Ls = (L & 7) * cpx + (L >> 3);
  const int bx = Ls % gx;
  const int tq = Ls / gx;
  const int by = tq % gy;
  const int eb = tq / gy;

  const size_t Ks2 = (size_t)K * 2;
  const char* Ag = (const char*)(A + (size_t)eb * MO * K + (size_t)by * 256 * K);
  const char* Bg = (const char*)(Bt + (size_t)eb * NO * K + (size_t)bx * 256 * K);
  const int rl = tid >> 3;
  const int sb = ((tid & 7) * 16) ^ ((rl & 7) << 4);  // pre-swizzled src byte col (T2)
  Ag += (size_t)rl * Ks2 + sb;
  Bg += (size_t)rl * Ks2 + sb;
  char* AsB = ((char*)As) + tid * 16;
  char* BsB = ((char*)Bs) + tid * 16;
  const u16* AsE = &As[0][0];
  const u16* BsE = &Bs[0][0];
  const int fr = lane & 15, kg8 = (lane >> 4) * 8;
  const int swz = (fr & 7) << 3;  // read-side element XOR (T2)

#define STAGE_A(BUF_, REG_, KT_) \
  gll16(Ag + (size_t)((REG_)*64) * Ks2 + (size_t)(KT_)*128, AsB + (BUF_)*32768 + (REG_)*8192)
#define STAGE_B(BUF_, REG_, KT_) \
  gll16(Bg + (size_t)((REG_)*64) * Ks2 + (size_t)(KT_)*128, BsB + (BUF_)*32768 + (REG_)*8192)
#define LDA(BUF_, M_, K_) \
  (*(const bf16x8*)&AsE[(BUF_)*16384 + (wm * 128 + (M_)*16 + fr) * 64 + (((K_)*32 + kg8) ^ swz)])
#define LDB(BUF_, N_, K_) \
  (*(const bf16x8*)&BsE[(BUF_)*16384 + (wn * 64 + (N_)*16 + fr) * 64 + (((K_)*32 + kg8) ^ swz)])
// k OUTER: 8 independent MFMAs per k-step (dependent pairs 8 apart)
#define MFMA_Q(MB_, NB_)                                                            \
  _Pragma("unroll") for (int k = 0; k < 2; ++k)                                     \
  _Pragma("unroll") for (int m = 0; m < 4; ++m)                                     \
  _Pragma("unroll") for (int n = 0; n < 2; ++n)                                     \
      acc[(MB_) + m][(NB_) + n] = __builtin_amdgcn_mfma_f32_16x16x32_bf16(          \
          areg[m][k], breg[(NB_) + n][k], acc[(MB_) + m][(NB_) + n], 0, 0, 0)

#define RD_A03(C_)                                                \
  _Pragma("unroll") for (int m = 0; m < 4; ++m) {                 \
    areg[m][0] = LDA(C_, m, 0); areg[m][1] = LDA(C_, m, 1);       \
  }
#define RD_A47(C_)                                                \
  _Pragma("unroll") for (int m = 0; m < 4; ++m) {                 \
    areg[m][0] = LDA(C_, 4 + m, 0); areg[m][1] = LDA(C_, 4 + m, 1); \
  }
#define RD_B01(C_)                                                \
  _Pragma("unroll") for (int n = 0; n < 2; ++n) {                 \
    breg[n][0] = LDB(C_, n, 0); breg[n][1] = LDB(C_, n, 1);       \
  }
#define RD_B23(C_)                                                \
  _Pragma("unroll") for (int n = 2; n < 4; ++n) {                 \
    breg[n][0] = LDB(C_, n, 0); breg[n][1] = LDB(C_, n, 1);       \
  }
// barrier -> lgkm(0) -> sched fence -> prio-boosted 16-MFMA quadrant -> barrier
#define MM(MB_, NB_)                          \
  BAR();                                      \
  LGKM(0);                                    \
  __builtin_amdgcn_sched_barrier(0);          \
  __builtin_amdgcn_s_setprio(1);              \
  MFMA_Q(MB_, NB_);                           \
  __builtin_amdgcn_s_setprio(0);              \
  BAR();

  f32x4 acc[8][4];
#pragma unroll
  for (int i = 0; i < 8; ++i)
#pragma unroll
    for (int j = 0; j < 4; ++j) acc[i][j] = {0.f, 0.f, 0.f, 0.f};
  bf16x8 areg[4][2], breg[4][2];

  const int NT = K >> 6;  // >= 2, even

  // prologue: tile0 full (8) + tile1 pairs #1-3 (6); vmcnt(6) retires tile0.
  STAGE_A(0, 0, 0); STAGE_A(0, 1, 0); STAGE_A(0, 2, 0); STAGE_A(0, 3, 0);
  STAGE_B(0, 0, 0); STAGE_B(0, 1, 0); STAGE_B(0, 2, 0); STAGE_B(0, 3, 0);
  STAGE_A(1, 0, 1); STAGE_A(1, 2, 1);
  STAGE_B(1, 0, 1); STAGE_B(1, 1, 1);
  STAGE_B(1, 2, 1); STAGE_B(1, 3, 1);
  VMCNT(6);
  BAR();

  for (int t = 0; t < NT; t += 2) {
    const int t2 = (t + 2 < NT) ? t + 2 : NT - 2;  // tail: identical-data re-stage
    const int t3 = (t + 3 < NT) ? t + 3 : NT - 1;
    // ---- K-tile t (buf0) ----
    RD_A03(0); RD_B01(0);
    STAGE_A(1, 1, t + 1); STAGE_A(1, 3, t + 1);
    LGKM(8);
    MM(0, 0);
    RD_B23(0);
    STAGE_A(0, 0, t2); STAGE_A(0, 2, t2);
    MM(0, 2);
    RD_A47(0);
    STAGE_B(0, 0, t2); STAGE_B(0, 1, t2);
    MM(4, 0);
    STAGE_B(0, 2, t2); STAGE_B(0, 3, t2);
    VMCNT(6);
    MM(4, 2);
    // ---- K-tile t+1 (buf1) ----
    RD_A03(1); RD_B01(1);
    STAGE_A(0, 1, t2); STAGE_A(0, 3, t2);
    LGKM(8);
    MM(0, 0);
    RD_B23(1);
    STAGE_A(1, 0, t3); STAGE_A(1, 2, t3);
    MM(0, 2);
    RD_A47(1);
    STAGE_B(1, 0, t3); STAGE_B(1, 1, t3);
    MM(4, 0);
    STAGE_B(1, 2, t3); STAGE_B(1, 3, t3);
    VMCNT(6);
    MM(4, 2);
  }

  // epilogue: C row = row0 + m*16 + r, col = col0 + n*16
  const int row0 = by * 256 + wm * 128 + (kg8 >> 3) * 4;
  const int col0 = bx * 256 + wn * 64 + fr;
  const float* be = bias + (size_t)eb * NO;
  size_t cbase = (size_t)eb * MO * NO;
#pragma unroll
  for (int m = 0; m < 8; ++m) {
#pragma unroll
    for (int n = 0; n < 4; ++n) {
      int col = col0 + n * 16;
      float bv = be[col];
#pragma unroll
      for (int r = 0; r < 4; ++r) {
        int row = row0 + m * 16 + r;
        float v = acc[m][n][r] + bv;
        if (RELU) v = fmaxf(v, 0.f);
        if (OUTBF16)
          ((u16*)Cv)[cbase + (size_t)row * NO + col] = f2bf(v);
        else
          ((float*)Cv)[cbase + (size_t)row * NO + col] = v;
      }
    }
  }
#undef MM
#undef RD_A03
#undef RD_A47
#undef RD_B01
#undef RD_B23
#undef STAGE_A
#undef STAGE_B
#undef LDA
#undef LDB
#undef MFMA_Q
}

// ------------- combine: out[t] = g1*eo[slot1] + g2*eo[slot2] (bf16 eo) -------------
__global__ void combine_kernel(const u16* __restrict__ eo,
                               const float* __restrict__ g1n, const float* __restrict__ g2n,
                               const int* __restrict__ slot1, const int* __restrict__ slot2,
                               float* __restrict__ out) {
  int t = blockIdx.x, tid = threadIdx.x;  // 256 threads x 4 fp32
  float g1 = g1n[t], g2 = g2n[t];
  int s1 = slot1[t], s2 = slot2[t];
  float o0 = 0.f, o1 = 0.f, o2 = 0.f, o3 = 0.f;
  if (s1 >= 0) {
    ushort4 a = ((const ushort4*)(eo + (size_t)s1 * DM))[tid];
    o0 = g1 * bf2f(a.x); o1 = g1 * bf2f(a.y); o2 = g1 * bf2f(a.z); o3 = g1 * bf2f(a.w);
  }
  if (s2 >= 0) {
    ushort4 b = ((const ushort4*)(eo + (size_t)s2 * DM))[tid];
    o0 += g2 * bf2f(b.x); o1 += g2 * bf2f(b.y); o2 += g2 * bf2f(b.z); o3 += g2 * bf2f(b.w);
  }
  ((float4*)(out + (size_t)t * DM))[tid] = make_float4(o0, o1, o2, o3);
}

extern "C" void kernel_launch(void* const* d_in, const int* in_sizes, int n_in,
                              void* d_out, int out_size, void* d_ws, size_t ws_size,
                              hipStream_t stream) {
  const float* x = (const float*)d_in[0];
  const float* wg = (const float*)d_in[1];
  const float* w1 = (const float*)d_in[2];
  const float* b1 = (const float*)d_in[3];
  const float* w2 = (const float*)d_in[4];
  const float* b2 = (const float*)d_in[5];
  float* out = (float*)d_out;

  const size_t SZ_WT1 = (size_t)NE * DH * DM * 2;   // 64 MB bf16 (aliased: eo bf16 32 MB)
  const size_t SZ_WT2 = (size_t)NE * DM * DH * 2;   // 64 MB
  const size_t SZ_XE = (size_t)NE * CAP * DM * 2;   // 32 MB
  const size_t SZ_H = (size_t)NE * CAP * DH * 2;    // 128 MB
  const size_t SZ_TOK = (size_t)TOKENS * 4;

  char* p = (char*)d_ws;
  u16* wt1 = (u16*)p;               // aliased region: wt1 (gemm1) then eo bf16 (gemm2)
  u16* eo = (u16*)p;                p += SZ_WT1;
  u16* wt2 = (u16*)p;               p += SZ_WT2;
  u16* xe = (u16*)p;                p += SZ_XE;
  u16* h = (u16*)p;                 p += SZ_H;
  int* idx1 = (int*)p;              p += SZ_TOK;
  int* idx2 = (int*)p;              p += SZ_TOK;
  int* slot1 = (int*)p;             p += SZ_TOK;
  int* slot2 = (int*)p;             p += SZ_TOK;
  float* g1r = (float*)p;           p += SZ_TOK;
  float* g2r = (float*)p;           p += SZ_TOK;
  float* g1n = (float*)p;           p += SZ_TOK;
  float* g2n = (float*)p;           p += SZ_TOK;
  int* slot2tok = (int*)p;          p += (size_t)NE * CAP * 4;
  float* me = (float*)p;            p += 256;
  if ((size_t)(p - (char*)d_ws) > ws_size) return;  // ws too small: fail loudly via absmax

  hipMemsetAsync(me, 0, 32, stream);
  hipMemsetAsync(slot2tok, 0xFF, (size_t)NE * CAP * 4, stream);

  gating_kernel<<<TOKENS / 4, 256, 0, stream>>>(x, wg, idx1, idx2, g1r, g2r, me);
  scan_kernel<<<1, 1024, 0, stream>>>(idx1, idx2, g1r, g2r, me, slot1, slot2, g1n, g2n,
                                      slot2tok, out + (size_t)TOKENS * DM);
  // merged: w1 [E][1024][4096] -> wt1 [E][4096][1024]; w2 [E][4096][1024] -> wt2 [E][1024][4096]
  transpose2_kernel<<<dim3(DH / 64, DM / 64, 16), 256, 0, stream>>>(w1, w2, wt1, wt2);
  gather_kernel<<<dim3(CAP, NE), 128, 0, stream>>>(x, slot2tok, xe);
  // h = relu(xe @ w1 + b1)  : [E][2048][4096] bf16
  gemm_kernel<1, 1><<<dim3(DH / 256, CAP / 256, NE), 512, 0, stream>>>(xe, wt1, b1, (void*)h,
                                                                       CAP, DH, DM);
  // eo = h @ w2 + b2        : [E][2048][1024] bf16 (aliases wt1 region; gemm1 done)
  gemm_kernel<0, 1><<<dim3(DM / 256, CAP / 256, NE), 512, 0, stream>>>(h, wt2, b2, (void*)eo,
                                                                       CAP, DM, DH);
  combine_kernel<<<TOKENS, 256, 0, stream>>>(eo, g1n, g2n, slot1, slot2, out);
}

// Round 12
// 453.271 us; speedup vs baseline: 1.0542x; 1.0303x over previous
//
#include <hip/hip_runtime.h>
#include <stdint.h>

typedef unsigned short u16;
typedef __attribute__((ext_vector_type(8))) short bf16x8;
typedef __attribute__((ext_vector_type(4))) float f32x4;

#define TOKENS 8192
#define DM 1024
#define NE 8
#define DH 4096
#define CAP 2048

__device__ __forceinline__ u16 f2bf(float f) {
  unsigned int u = __float_as_uint(f);
  u = u + 0x7FFFu + ((u >> 16) & 1u);
  return (u16)(u >> 16);
}
__device__ __forceinline__ float bf2f(u16 u) {
  return __uint_as_float(((unsigned int)u) << 16);
}

__device__ __forceinline__ void gll16(const void* g, void* l) {
  __builtin_amdgcn_global_load_lds(
      (const __attribute__((address_space(1))) unsigned int*)g,
      (__attribute__((address_space(3))) unsigned int*)l, 16, 0, 0);
}

// ---------------- gating: logits (double accum) + softmax + top2 ----------------
// me via per-block partials (atomicAdd on 8 hot addresses serialized at L2).
__global__ __launch_bounds__(256) void gating_kernel(
    const float* __restrict__ x, const float* __restrict__ wg,
    int* __restrict__ idx1, int* __restrict__ idx2,
    float* __restrict__ g1r, float* __restrict__ g2r, float* __restrict__ mepart) {
  __shared__ float gsh[4][8];
  int lane = threadIdx.x & 63;
  int w = threadIdx.x >> 6;
  int t = blockIdx.x * 4 + w;
  const float* xr = x + (size_t)t * DM;
  double acc[8];
#pragma unroll
  for (int e = 0; e < 8; ++e) acc[e] = 0.0;
#pragma unroll
  for (int it = 0; it < 4; ++it) {
    float4 xv = ((const float4*)xr)[it * 64 + lane];
    int base = (it * 64 + lane) * 4;
    const float* wr = wg + (size_t)base * 8;
    float xs[4] = {xv.x, xv.y, xv.z, xv.w};
#pragma unroll
    for (int j = 0; j < 4; ++j)
#pragma unroll
      for (int e = 0; e < 8; ++e) acc[e] += (double)xs[j] * (double)wr[j * 8 + e];
  }
#pragma unroll
  for (int off = 32; off > 0; off >>= 1)
#pragma unroll
    for (int e = 0; e < 8; ++e) acc[e] += __shfl_down(acc[e], off);
  if (lane == 0) {
    float l[8];
#pragma unroll
    for (int e = 0; e < 8; ++e) l[e] = (float)acc[e];
    int i1 = 0;
    float v1 = l[0];
#pragma unroll
    for (int e = 1; e < 8; ++e)
      if (l[e] > v1) { v1 = l[e]; i1 = e; }
    int i2 = -1;
    float v2 = -3.4e38f;
#pragma unroll
    for (int e = 0; e < 8; ++e)
      if (e != i1 && l[e] > v2) { v2 = l[e]; i2 = e; }
    float s = 0.f;
    float p[8];
#pragma unroll
    for (int e = 0; e < 8; ++e) { p[e] = expf(l[e] - v1); s += p[e]; }
    float inv = 1.f / s;
    idx1[t] = i1;
    idx2[t] = i2;
    g1r[t] = inv;                    // p[i1] == 1
    g2r[t] = expf(v2 - v1) * inv;
#pragma unroll
    for (int e = 0; e < 8; ++e) gsh[w][e] = p[e] * inv;
  }
  __syncthreads();
  if (threadIdx.x < 8) {
    int e = threadIdx.x;
    mepart[blockIdx.x * 8 + e] = gsh[0][e] + gsh[1][e] + gsh[2][e] + gsh[3][e];
  }
}

// -------- single-block scan: per-expert exclusive prefix, capacity, slots, laux --------
__global__ __launch_bounds__(1024) void scan_kernel(
    const int* __restrict__ idx1, const int* __restrict__ idx2,
    const float* __restrict__ g1r, const float* __restrict__ g2r,
    const float* __restrict__ mepart,
    int* __restrict__ slot1, int* __restrict__ slot2,
    float* __restrict__ g1n, float* __restrict__ g2n,
    int* __restrict__ slot2tok, float* __restrict__ laux) {
  __shared__ u16 c[16][1024];
  __shared__ u16 csum[16][32];
  __shared__ int tot[16];
  __shared__ float mred[1024];
  int tid = threadIdx.x;
  int i1[8], i2[8];
#pragma unroll
  for (int ctr = 0; ctr < 16; ++ctr) c[ctr][tid] = 0;
#pragma unroll
  for (int j = 0; j < 8; ++j) {
    int t = tid * 8 + j;
    i1[j] = idx1[t];
    i2[j] = idx2[t];
    c[i1[j]][tid]++;
    c[8 + i2[j]][tid]++;
  }
  __syncthreads();
  if (tid < 512) {
    int ctr = tid >> 5, ch = tid & 31;
    int s = 0;
#pragma unroll
    for (int i = 0; i < 32; ++i) s += c[ctr][ch * 32 + i];
    csum[ctr][ch] = (u16)s;
  }
  __syncthreads();
  if (tid < 16) {
    int run = 0;
#pragma unroll
    for (int ch = 0; ch < 32; ++ch) {
      int v = csum[tid][ch];
      csum[tid][ch] = (u16)run;
      run += v;
    }
    tot[tid] = run;
  }
  __syncthreads();
  if (tid < 512) {
    int ctr = tid >> 5, ch = tid & 31;
    int run = csum[ctr][ch];
#pragma unroll
    for (int i = 0; i < 32; ++i) {
      int v = c[ctr][ch * 32 + i];
      c[ctr][ch * 32 + i] = (u16)run;
      run += v;
    }
  }
  __syncthreads();
#pragma unroll
  for (int j = 0; j < 8; ++j) {
    int t = tid * 8 + j;
    int e1 = i1[j], e2 = i2[j];
    int L1 = c[e1][tid]++;
    int L2 = c[8 + e2][tid]++;
    L2 += tot[e2];
    bool kv1 = L1 < CAP, kv2 = L2 < CAP;
    float G1 = kv1 ? g1r[t] : 0.f;
    float G2 = kv2 ? g2r[t] : 0.f;
    float den = fmaxf(G1 + G2, 1e-9f);
    g1n[t] = G1 / den;
    g2n[t] = G2 / den;
    int s1 = kv1 ? (e1 * CAP + L1) : -1;
    int s2 = kv2 ? (e2 * CAP + L2) : -1;
    slot1[t] = s1;
    slot2[t] = s2;
    if (kv1) slot2tok[s1] = t;
    if (kv2) slot2tok[s2] = t;
  }
  // reduce mepart [2048][8] -> per-expert totals (thread tid owns expert tid&7)
  {
    float macc = 0.f;
    int e = tid & 7;
    for (int r = tid >> 3; r < 2048; r += 128) macc += mepart[r * 8 + e];
    mred[tid] = macc;
  }
  __syncthreads();
  for (int s = 512; s >= 8; s >>= 1) {
    if (tid < s) mred[tid] += mred[tid + s];
    __syncthreads();
  }
  if (tid == 0) {
    double a = 0.0;
    for (int e = 0; e < 8; ++e)
      a += ((double)mred[e] / 8192.0) * ((double)tot[e] / 8192.0);
    laux[0] = (float)(a * 8.0);  // mean(me*ce)*E*E = (sum/8)*64
  }
}

// --- merged transpose: z<8 -> w1 expert z; z>=8 -> w2 expert z-8 (fp32->bf16, [R][C]->[C][R])
__global__ __launch_bounds__(256) void transpose2_kernel(
    const float* __restrict__ w1, const float* __restrict__ w2,
    u16* __restrict__ wt1, u16* __restrict__ wt2) {
  __shared__ float tile[64][65];
  const int tid = threadIdx.x;
  const int z = blockIdx.z;
  const float* s;
  u16* d;
  int C, r0, c0;
  if (z < 8) {
    s = w1 + (size_t)z * DM * DH;
    d = wt1 + (size_t)z * DM * DH;
    C = DH;  // R = DM
    r0 = blockIdx.y * 64;
    c0 = blockIdx.x * 64;
  } else {
    s = w2 + (size_t)(z - 8) * DM * DH;
    d = wt2 + (size_t)(z - 8) * DM * DH;
    C = DM;  // R = DH
    r0 = blockIdx.x * 64;
    c0 = blockIdx.y * 64;
  }
  const int R = (z < 8) ? DM : DH;
  const int lr = tid >> 4;          // 0..15
  const int lc = (tid & 15) * 4;    // 0..60
#pragma unroll
  for (int i = 0; i < 4; ++i) {
    const float4 v = *(const float4*)&s[(size_t)(r0 + i * 16 + lr) * C + c0 + lc];
    tile[i * 16 + lr][lc] = v.x;
    tile[i * 16 + lr][lc + 1] = v.y;
    tile[i * 16 + lr][lc + 2] = v.z;
    tile[i * 16 + lr][lc + 3] = v.w;
  }
  __syncthreads();
  const int oc = tid >> 3;        // 0..31 (output row = input col)
  const int orr = (tid & 7) * 8;  // 0..56 (output col base = input row)
#pragma unroll
  for (int i = 0; i < 2; ++i) {
    const int c = oc + i * 32;
    u16 o[8];
#pragma unroll
    for (int j = 0; j < 8; ++j) o[j] = f2bf(tile[orr + j][c]);
    *(uint4*)&d[(size_t)(c0 + c) * R + r0 + orr] = *(const uint4*)o;
  }
}

// ---------------- gather tokens to expert buffers (bf16) ----------------
__global__ void gather_kernel(const float* __restrict__ x, const int* __restrict__ slot2tok,
                              u16* __restrict__ xe) {
  int slot = blockIdx.y * CAP + blockIdx.x;
  int tok = slot2tok[slot];
  int tid = threadIdx.x;  // 128
  u16 o[8];
  if (tok >= 0) {
    const float4* xr = (const float4*)(x + (size_t)tok * DM);
    float4 a = xr[tid * 2], b = xr[tid * 2 + 1];
    o[0] = f2bf(a.x); o[1] = f2bf(a.y); o[2] = f2bf(a.z); o[3] = f2bf(a.w);
    o[4] = f2bf(b.x); o[5] = f2bf(b.y); o[6] = f2bf(b.z); o[7] = f2bf(b.w);
  } else {
#pragma unroll
    for (int j = 0; j < 8; ++j) o[j] = 0;
  }
  *(uint4*)(xe + (size_t)slot * DM + tid * 8) = *(const uint4*)o;
}

// ---- 256x256 deep-ILP bf16 GEMM (R4-verified: fastest measured dispatches) ----
// 1 barrier + 1 vmcnt(0) per K-tile; stage(t+1) issued first (full-tile skew to
// the wait), 24 ds_reads interleaved with 4 MFMA quadrants (compiler-counted
// lgkm). T1 XCD swizzle + T2 LDS swizzle (0 bank conflicts measured).
// Structural plateau note: five schedule variants (2-phase, 8-phase shallow/
// m201-faithful, 1-barrier deep-ILP, B-read-ahead) all measure 166-180 us —
// sum-of-pipes bound (MFMA 2480 + LDS-read ~2260 cyc/K-tile) at 1 block/CU.
#define BAR()                              \
  {                                        \
    asm volatile("" ::: "memory");         \
    __builtin_amdgcn_s_barrier();          \
    asm volatile("" ::: "memory");         \
  }
#define VMCNT(n) asm volatile("s_waitcnt vmcnt(" #n ")" ::: "memory")

template <int RELU, int OUTBF16>
__global__ __launch_bounds__(512, 2) void gemm_kernel(
    const u16* __restrict__ A, const u16* __restrict__ Bt,
    const float* __restrict__ bias, void* __restrict__ Cv,
    int MO, int NO, int K) {
  __shared__ __align__(16) u16 As[2][256 * 64];
  __shared__ __align__(16) u16 Bs[2][256 * 64];
  const int tid = threadIdx.x;
  const int lane = tid & 63, wid = tid >> 6;
  const int wm = wid >> 2, wn = wid & 3;

  // T1: XCD-bijective swizzle — XCD k owns a contiguous x-major chunk (= expert k).
  const int gx = gridDim.x, gy = gridDim.y;
  const int nwg = gx * gy * gridDim.z;      // multiple of 8
  const int L = (blockIdx.z * gy + blockIdx.y) * gx + blockIdx.x;
  const int cpx = nwg >> 3;
  const int Ls = (L & 7) * cpx + (L >> 3);
  const int bx = Ls % gx;
  const int tq = Ls / gx;
  const int by = tq % gy;
  const int eb = tq / gy;

  const size_t Ks2 = (size_t)K * 2;
  const char* Ag = (const char*)(A + (size_t)eb * MO * K + (size_t)by * 256 * K);
  const char* Bg = (const char*)(Bt + (size_t)eb * NO * K + (size_t)bx * 256 * K);
  const int rl = tid >> 3;
  const int sb = ((tid & 7) * 16) ^ ((rl & 7) << 4);  // pre-swizzled src byte col (T2)
  Ag += (size_t)rl * Ks2 + sb;
  Bg += (size_t)rl * Ks2 + sb;
  char* AsB = ((char*)As) + tid * 16;
  char* BsB = ((char*)Bs) + tid * 16;
  const u16* AsE = &As[0][0];
  const u16* BsE = &Bs[0][0];
  const int fr = lane & 15, kg8 = (lane >> 4) * 8;
  const int swz = (fr & 7) << 3;  // read-side element XOR (T2)

#define STAGE_A(BUF_, REG_, KT_) \
  gll16(Ag + (size_t)((REG_)*64) * Ks2 + (size_t)(KT_)*128, AsB + (BUF_)*32768 + (REG_)*8192)
#define STAGE_B(BUF_, REG_, KT_) \
  gll16(Bg + (size_t)((REG_)*64) * Ks2 + (size_t)(KT_)*128, BsB + (BUF_)*32768 + (REG_)*8192)
#define LDA(BUF_, M_, K_) \
  (*(const bf16x8*)&AsE[(BUF_)*16384 + (wm * 128 + (M_)*16 + fr) * 64 + (((K_)*32 + kg8) ^ swz)])
#define LDB(BUF_, N_, K_) \
  (*(const bf16x8*)&BsE[(BUF_)*16384 + (wn * 64 + (N_)*16 + fr) * 64 + (((K_)*32 + kg8) ^ swz)])
// k OUTER: 8 independent MFMAs per k-step (dependent pairs 8 apart)
#define MFMA_Q(MB_, NB_)                                                            \
  _Pragma("unroll") for (int k = 0; k < 2; ++k)                                     \
  _Pragma("unroll") for (int m = 0; m < 4; ++m)                                     \
  _Pragma("unroll") for (int n = 0; n < 2; ++n)                                     \
      acc[(MB_) + m][(NB_) + n] = __builtin_amdgcn_mfma_f32_16x16x32_bf16(          \
          areg[m][k], breg[(NB_) + n][k], acc[(MB_) + m][(NB_) + n], 0, 0, 0)

  f32x4 acc[8][4];
#pragma unroll
  for (int i = 0; i < 8; ++i)
#pragma unroll
    for (int j = 0; j < 4; ++j) acc[i][j] = {0.f, 0.f, 0.f, 0.f};
  bf16x8 areg[4][2], breg[4][2];

  const int NT = K >> 6;

#define TILE_STEP(CUR_, NXT_, ST_)                                                  \
  {                                                                                 \
    /* stage t+1 -> NXT first: starts VMEM latency earliest */                      \
    STAGE_A(NXT_, 0, ST_); STAGE_A(NXT_, 1, ST_);                                   \
    STAGE_A(NXT_, 2, ST_); STAGE_A(NXT_, 3, ST_);                                   \
    STAGE_B(NXT_, 0, ST_); STAGE_B(NXT_, 1, ST_);                                   \
    STAGE_B(NXT_, 2, ST_); STAGE_B(NXT_, 3, ST_);                                   \
    /* 16 ds_reads: A m0-3 (k0,k1), B n0-3 (k0,k1) */                               \
    _Pragma("unroll") for (int m = 0; m < 4; ++m) {                                 \
      areg[m][0] = LDA(CUR_, m, 0); areg[m][1] = LDA(CUR_, m, 1);                   \
    }                                                                               \
    _Pragma("unroll") for (int n = 0; n < 4; ++n) {                                 \
      breg[n][0] = LDB(CUR_, n, 0); breg[n][1] = LDB(CUR_, n, 1);                   \
    }                                                                               \
    __builtin_amdgcn_s_setprio(1);                                                  \
    MFMA_Q(0, 0); MFMA_Q(0, 2);                                                     \
    __builtin_amdgcn_s_setprio(0);                                                  \
    /* 8 ds_reads: A m4-7 (reg reuse; compiler handles WAR) */                      \
    _Pragma("unroll") for (int m = 0; m < 4; ++m) {                                 \
      areg[m][0] = LDA(CUR_, 4 + m, 0); areg[m][1] = LDA(CUR_, 4 + m, 1);           \
    }                                                                               \
    __builtin_amdgcn_s_setprio(1);                                                  \
    MFMA_Q(4, 0); MFMA_Q(4, 2);                                                     \
    __builtin_amdgcn_s_setprio(0);                                                  \
    VMCNT(0); /* own staging retired; issue-to-wait = full tile of MFMA */          \
    BAR();    /* all waves' staging visible; NXT safe to read next tile */          \
  }

  // prologue: tile 0 -> buf 0
  STAGE_A(0, 0, 0); STAGE_A(0, 1, 0); STAGE_A(0, 2, 0); STAGE_A(0, 3, 0);
  STAGE_B(0, 0, 0); STAGE_B(0, 1, 0); STAGE_B(0, 2, 0); STAGE_B(0, 3, 0);
  VMCNT(0);
  BAR();

  for (int t = 0; t < NT; t += 2) {
    const int s1 = (t + 1 < NT) ? t + 1 : NT - 1;  // tail: junk re-stage, dead buf
    const int s2 = (t + 2 < NT) ? t + 2 : NT - 1;
    TILE_STEP(0, 1, s1);
    TILE_STEP(1, 0, s2);
  }

  // epilogue: C row = row0 + m*16 + r, col = col0 + n*16
  const int row0 = by * 256 + wm * 128 + (kg8 >> 3) * 4;
  const int col0 = bx * 256 + wn * 64 + fr;
  const float* be = bias + (size_t)eb * NO;
  size_t cbase = (size_t)eb * MO * NO;
#pragma unroll
  for (int m = 0; m < 8; ++m) {
#pragma unroll
    for (int n = 0; n < 4; ++n) {
      int col = col0 + n * 16;
      float bv = be[col];
#pragma unroll
      for (int r = 0; r < 4; ++r) {
        int row = row0 + m * 16 + r;
        float v = acc[m][n][r] + bv;
        if (RELU) v = fmaxf(v, 0.f);
        if (OUTBF16)
          ((u16*)Cv)[cbase + (size_t)row * NO + col] = f2bf(v);
        else
          ((float*)Cv)[cbase + (size_t)row * NO + col] = v;
      }
    }
  }
#undef TILE_STEP
#undef STAGE_A
#undef STAGE_B
#undef LDA
#undef LDB
#undef MFMA_Q
}

// ------------- combine: out[t] = g1*eo[slot1] + g2*eo[slot2] (bf16 eo) -------------
__global__ void combine_kernel(const u16* __restrict__ eo,
                               const float* __restrict__ g1n, const float* __restrict__ g2n,
                               const int* __restrict__ slot1, const int* __restrict__ slot2,
                               float* __restrict__ out) {
  int t = blockIdx.x, tid = threadIdx.x;  // 256 threads x 4 fp32
  float g1 = g1n[t], g2 = g2n[t];
  int s1 = slot1[t], s2 = slot2[t];
  float o0 = 0.f, o1 = 0.f, o2 = 0.f, o3 = 0.f;
  if (s1 >= 0) {
    ushort4 a = ((const ushort4*)(eo + (size_t)s1 * DM))[tid];
    o0 = g1 * bf2f(a.x); o1 = g1 * bf2f(a.y); o2 = g1 * bf2f(a.z); o3 = g1 * bf2f(a.w);
  }
  if (s2 >= 0) {
    ushort4 b = ((const ushort4*)(eo + (size_t)s2 * DM))[tid];
    o0 += g2 * bf2f(b.x); o1 += g2 * bf2f(b.y); o2 += g2 * bf2f(b.z); o3 += g2 * bf2f(b.w);
  }
  ((float4*)(out + (size_t)t * DM))[tid] = make_float4(o0, o1, o2, o3);
}

extern "C" void kernel_launch(void* const* d_in, const int* in_sizes, int n_in,
                              void* d_out, int out_size, void* d_ws, size_t ws_size,
                              hipStream_t stream) {
  const float* x = (const float*)d_in[0];
  const float* wg = (const float*)d_in[1];
  const float* w1 = (const float*)d_in[2];
  const float* b1 = (const float*)d_in[3];
  const float* w2 = (const float*)d_in[4];
  const float* b2 = (const float*)d_in[5];
  float* out = (float*)d_out;

  const size_t SZ_WT1 = (size_t)NE * DH * DM * 2;   // 64 MB bf16 (aliased: eo bf16 32 MB)
  const size_t SZ_WT2 = (size_t)NE * DM * DH * 2;   // 64 MB
  const size_t SZ_XE = (size_t)NE * CAP * DM * 2;   // 32 MB
  const size_t SZ_H = (size_t)NE * CAP * DH * 2;    // 128 MB
  const size_t SZ_TOK = (size_t)TOKENS * 4;

  char* p = (char*)d_ws;
  u16* wt1 = (u16*)p;               // aliased region: wt1 (gemm1) then eo bf16 (gemm2)
  u16* eo = (u16*)p;                p += SZ_WT1;
  u16* wt2 = (u16*)p;               p += SZ_WT2;
  u16* xe = (u16*)p;                p += SZ_XE;
  u16* h = (u16*)p;                 p += SZ_H;
  int* idx1 = (int*)p;              p += SZ_TOK;
  int* idx2 = (int*)p;              p += SZ_TOK;
  int* slot1 = (int*)p;             p += SZ_TOK;
  int* slot2 = (int*)p;             p += SZ_TOK;
  float* g1r = (float*)p;           p += SZ_TOK;
  float* g2r = (float*)p;           p += SZ_TOK;
  float* g1n = (float*)p;           p += SZ_TOK;
  float* g2n = (float*)p;           p += SZ_TOK;
  int* slot2tok = (int*)p;          p += (size_t)NE * CAP * 4;
  float* mepart = (float*)p;        p += (size_t)2048 * 8 * 4;
  if ((size_t)(p - (char*)d_ws) > ws_size) return;  // ws too small: fail loudly via absmax

  hipMemsetAsync(slot2tok, 0xFF, (size_t)NE * CAP * 4, stream);

  gating_kernel<<<TOKENS / 4, 256, 0, stream>>>(x, wg, idx1, idx2, g1r, g2r, mepart);
  scan_kernel<<<1, 1024, 0, stream>>>(idx1, idx2, g1r, g2r, mepart, slot1, slot2, g1n, g2n,
                                      slot2tok, out + (size_t)TOKENS * DM);
  // merged: w1 [E][1024][4096] -> wt1 [E][4096][1024]; w2 [E][4096][1024] -> wt2 [E][1024][4096]
  transpose2_kernel<<<dim3(DH / 64, DM / 64, 16), 256, 0, stream>>>(w1, w2, wt1, wt2);
  gather_kernel<<<dim3(CAP, NE), 128, 0, stream>>>(x, slot2tok, xe);
  // h = relu(xe @ w1 + b1)  : [E][2048][4096] bf16
  gemm_kernel<1, 1><<<dim3(DH / 256, CAP / 256, NE), 512, 0, stream>>>(xe, wt1, b1, (void*)h,
                                                                       CAP, DH, DM);
  // eo = h @ w2 + b2        : [E][2048][1024] bf16 (aliases wt1 region; gemm1 done)
  gemm_kernel<0, 1><<<dim3(DM / 256, CAP / 256, NE), 512, 0, stream>>>(h, wt2, b2, (void*)eo,
                                                                       CAP, DM, DH);
  combine_kernel<<<TOKENS, 256, 0, stream>>>(eo, g1n, g2n, slot1, slot2, out);
}